// Round 2
// baseline (851.574 us; speedup 1.0000x reference)
//
#include <hip/hip_runtime.h>

#define N_NODES 100000
#define N_EDGES 50000
#define NNZ     3200000
#define D       32
#define SCAN_B  1024
#define N_SBLK  ((N_NODES + SCAN_B - 1) / SCAN_B)   // 98

// ---------------------------------------------------------------------------
// K0: fuse weights.  M1 = W1 @ W2b, c1 = b1 @ W2b, A2 = W2a @ W, c2 = b2 @ W
// ---------------------------------------------------------------------------
__global__ void k0_weights(const float* __restrict__ W1, const float* __restrict__ b1,
                           const float* __restrict__ W2, const float* __restrict__ b2,
                           const float* __restrict__ Ww,
                           float* __restrict__ M1, float* __restrict__ c1,
                           float* __restrict__ A2, float* __restrict__ c2) {
    int t = threadIdx.x;            // 1024 threads
    int k = t >> 5, dd = t & 31;
    float m = 0.f, a = 0.f;
#pragma unroll
    for (int j = 0; j < D; ++j) {
        m = fmaf(W1[k * D + j], W2[(D + j) * D + dd], m);   // W1 @ W2b
        a = fmaf(W2[k * D + j], Ww[j * D + dd], a);          // W2a @ W
    }
    M1[k * D + dd] = m;
    A2[k * D + dd] = a;
    if (k == 0) {
        float cc1 = 0.f, cc2 = 0.f;
#pragma unroll
        for (int j = 0; j < D; ++j) {
            cc1 = fmaf(b1[j], W2[(D + j) * D + dd], cc1);
            cc2 = fmaf(b2[j], Ww[j * D + dd], cc2);
        }
        c1[dd] = cc1;
        c2[dd] = cc2;
    }
}

// ---------------------------------------------------------------------------
// Histogram of vertex -> cnt
// ---------------------------------------------------------------------------
__global__ void k_hist(const int* __restrict__ vertex, int* __restrict__ cnt) {
    int i = blockIdx.x * blockDim.x + threadIdx.x;
    int stride = gridDim.x * blockDim.x;
    for (; i < NNZ; i += stride) atomicAdd(&cnt[vertex[i]], 1);
}

// ---------------------------------------------------------------------------
// 2-level exclusive scan of cnt -> cur  (cur = exclusive offsets)
// ---------------------------------------------------------------------------
__global__ void scan_a(const int* __restrict__ cnt, int* __restrict__ cur,
                       int* __restrict__ bsum) {
    __shared__ int s[SCAN_B];
    int i = blockIdx.x * SCAN_B + threadIdx.x;
    int v = (i < N_NODES) ? cnt[i] : 0;
    s[threadIdx.x] = v;
    __syncthreads();
    for (int off = 1; off < SCAN_B; off <<= 1) {
        int t = (threadIdx.x >= off) ? s[threadIdx.x - off] : 0;
        __syncthreads();
        s[threadIdx.x] += t;
        __syncthreads();
    }
    if (i < N_NODES) cur[i] = s[threadIdx.x] - v;          // exclusive in block
    if (threadIdx.x == SCAN_B - 1) bsum[blockIdx.x] = s[SCAN_B - 1];
}

__global__ void scan_b(int* __restrict__ bsum) {
    __shared__ int s[128];
    int t = threadIdx.x;
    int v = (t < N_SBLK) ? bsum[t] : 0;
    s[t] = v;
    __syncthreads();
    for (int off = 1; off < 128; off <<= 1) {
        int u = (t >= off) ? s[t - off] : 0;
        __syncthreads();
        s[t] += u;
        __syncthreads();
    }
    if (t < N_SBLK) bsum[t] = s[t] - v;                    // exclusive block offsets
}

__global__ void scan_c(int* __restrict__ cur, const int* __restrict__ bsum) {
    int i = blockIdx.x * SCAN_B + threadIdx.x;
    if (i < N_NODES) cur[i] += bsum[blockIdx.x];
}

// ---------------------------------------------------------------------------
// CSR fill: csr[slot] = edge id, grouped by vertex (order within group arbitrary)
// ---------------------------------------------------------------------------
__global__ void k_fill(const int* __restrict__ vertex, const int* __restrict__ edges,
                       int* __restrict__ cur, int* __restrict__ csr) {
    int i = blockIdx.x * blockDim.x + threadIdx.x;
    if (i >= NNZ) return;
    int v = vertex[i];
    int p = atomicAdd(&cur[v], 1);
    csr[p] = edges[i];
}

// ---------------------------------------------------------------------------
// K2: per-edge (wave per edge, sorted-edges segment via binary search).
//   Fe[e] = (sum_i a_i * X[v_i]) @ M1 + (sum_i a_i) * c1
// ---------------------------------------------------------------------------
__global__ void k2_edge(const float* __restrict__ X,
                        const float* __restrict__ atts,
                        const int* __restrict__ vertex,
                        const int* __restrict__ edges,
                        const float* __restrict__ M1,
                        const float* __restrict__ c1,
                        float* __restrict__ Fe) {
    __shared__ float Ms[D * D];
    __shared__ float cs[D];
    for (int i = threadIdx.x; i < D * D; i += blockDim.x) Ms[i] = M1[i];
    if (threadIdx.x < D) cs[threadIdx.x] = c1[threadIdx.x];
    __syncthreads();

    int wave = threadIdx.x >> 6;
    int lane = threadIdx.x & 63;
    int d    = lane & 31;
    int h    = lane >> 5;
    int e    = blockIdx.x * (blockDim.x >> 6) + wave;
    if (e >= N_EDGES) return;

    int lo = 0, hi = NNZ;
    while (lo < hi) { int mid = (lo + hi) >> 1; if (edges[mid] < e) lo = mid + 1; else hi = mid; }
    int start = lo;
    hi = NNZ;
    while (lo < hi) { int mid = (lo + hi) >> 1; if (edges[mid] < e + 1) lo = mid + 1; else hi = mid; }
    int end = lo;

    float acc = 0.f, sa = 0.f;
    for (int i = start + h; i < end; i += 2) {
        int   v = vertex[i];
        float a = atts[i];
        acc = fmaf(a, X[v * D + d], acc);
        sa += a;
    }
    acc += __shfl(acc, lane ^ 32, 64);
    sa  += __shfl(sa,  lane ^ 32, 64);

    float fe = sa * cs[d];
#pragma unroll
    for (int k = 0; k < D; ++k) {
        float xk = __shfl(acc, k, 32);
        fe = fmaf(xk, Ms[k * D + d], fe);
    }
    if (h == 0) Fe[e * D + d] = fe;
}

// ---------------------------------------------------------------------------
// K3: per-node (half-wave per node).
//   Sf = sum over csr segment of Fe[e]
//   out = 0.5*(deg*(X@A2 + c2) + (Sf + X0)@W) + b
// ---------------------------------------------------------------------------
__global__ void k3_node(const float* __restrict__ X,
                        const float* __restrict__ X0,
                        const float* __restrict__ Fe,
                        const int* __restrict__ cnt,
                        const int* __restrict__ cur,   // = offset + cnt after fill
                        const int* __restrict__ csr,
                        const float* __restrict__ A2,
                        const float* __restrict__ c2,
                        const float* __restrict__ Ww,
                        const float* __restrict__ bw,
                        float* __restrict__ out) {
    __shared__ float As[D * D];
    __shared__ float Ws[D * D];
    __shared__ float c2s[D];
    __shared__ float bws[D];
    for (int i = threadIdx.x; i < D * D; i += blockDim.x) {
        As[i] = A2[i];
        Ws[i] = Ww[i];
    }
    if (threadIdx.x < D) { c2s[threadIdx.x] = c2[threadIdx.x]; bws[threadIdx.x] = bw[threadIdx.x]; }
    __syncthreads();

    int half = threadIdx.x >> 5;
    int j    = threadIdx.x & 31;
    int node = blockIdx.x * (blockDim.x >> 5) + half;
    if (node >= N_NODES) return;

    int dg = cnt[node];
    int st = cur[node] - dg;

    float sf = 0.f;
    for (int i = 0; i < dg; ++i) {
        int e = csr[st + i];
        sf += Fe[e * D + j];
    }

    float x  = X[node * D + j];
    float s1 = c2s[j];
#pragma unroll
    for (int k = 0; k < D; ++k) {
        float xk = __shfl(x, k, 32);
        s1 = fmaf(xk, As[k * D + j], s1);
    }

    float t  = sf + X0[node * D + j];
    float s2 = 0.f;
#pragma unroll
    for (int k = 0; k < D; ++k) {
        float tk = __shfl(t, k, 32);
        s2 = fmaf(tk, Ws[k * D + j], s2);
    }

    out[node * D + j] = 0.5f * (fmaf((float)dg, s1, s2)) + bws[j];
}

// ---------------------------------------------------------------------------
extern "C" void kernel_launch(void* const* d_in, const int* in_sizes, int n_in,
                              void* d_out, int out_size, void* d_ws, size_t ws_size,
                              hipStream_t stream) {
    const float* X      = (const float*)d_in[0];
    const float* X0     = (const float*)d_in[1];
    const float* atts   = (const float*)d_in[2];
    const float* W1w    = (const float*)d_in[3];
    const float* W1b    = (const float*)d_in[4];
    const float* W2w    = (const float*)d_in[5];
    const float* W2b    = (const float*)d_in[6];
    const float* Ww     = (const float*)d_in[7];
    const float* Wb     = (const float*)d_in[8];
    const int*   vertex = (const int*)d_in[9];
    const int*   edges  = (const int*)d_in[10];
    float*       out    = (float*)d_out;

    char* ws = (char*)d_ws;
    float* M1   = (float*)(ws + 0);            // 4 KB
    float* A2   = (float*)(ws + 4096);         // 4 KB
    float* c1   = (float*)(ws + 8192);         // 128 B
    float* c2   = (float*)(ws + 8320);         // 128 B
    int*   bsum = (int*)  (ws + 8704);         // 512 B
    int*   cnt  = (int*)  (ws + 16384);        // 400 KB
    int*   cur  = (int*)  (ws + 416384);       // 400 KB
    int*   csr  = (int*)  (ws + 816384);       // 12.8 MB
    float* Fe   = (float*)(ws + 13616384);     // 6.4 MB   (total ~20 MB)

    hipMemsetAsync(cnt, 0, (size_t)N_NODES * 4, stream);

    k0_weights<<<1, 1024, 0, stream>>>(W1w, W1b, W2w, W2b, Ww, M1, c1, A2, c2);
    k_hist    <<<1024, 256, 0, stream>>>(vertex, cnt);
    scan_a    <<<N_SBLK, SCAN_B, 0, stream>>>(cnt, cur, bsum);
    scan_b    <<<1, 128, 0, stream>>>(bsum);
    scan_c    <<<N_SBLK, SCAN_B, 0, stream>>>(cur, bsum);
    k_fill    <<<(NNZ + 255) / 256, 256, 0, stream>>>(vertex, edges, cur, csr);
    k2_edge   <<<(N_EDGES + 3) / 4, 256, 0, stream>>>(X, atts, vertex, edges, M1, c1, Fe);
    k3_node   <<<(N_NODES + 7) / 8, 256, 0, stream>>>(X, X0, Fe, cnt, cur, csr, A2, c2, Ww, Wb, out);
}

// Round 3
// 395.005 us; speedup vs baseline: 2.1559x; 2.1559x over previous
//
#include <hip/hip_runtime.h>
#include <hip/hip_fp16.h>

#define N_NODES 100000
#define N_EDGES 50000
#define NNZ     3200000
#define D       32

// ---------------------------------------------------------------------------
// K0: fuse weights.  M1 = W1 @ W2b, c1 = b1 @ W2b, A2 = W2a @ W, c2 = b2 @ W
// ---------------------------------------------------------------------------
__global__ void k0_weights(const float* __restrict__ W1, const float* __restrict__ b1,
                           const float* __restrict__ W2, const float* __restrict__ b2,
                           const float* __restrict__ Ww,
                           float* __restrict__ M1, float* __restrict__ c1,
                           float* __restrict__ A2, float* __restrict__ c2) {
    int t = threadIdx.x;            // 1024 threads
    int k = t >> 5, dd = t & 31;
    float m = 0.f, a = 0.f;
#pragma unroll
    for (int j = 0; j < D; ++j) {
        m = fmaf(W1[k * D + j], W2[(D + j) * D + dd], m);   // W1 @ W2b
        a = fmaf(W2[k * D + j], Ww[j * D + dd], a);          // W2a @ W
    }
    M1[k * D + dd] = m;
    A2[k * D + dd] = a;
    if (k == 0) {
        float cc1 = 0.f, cc2 = 0.f;
#pragma unroll
        for (int j = 0; j < D; ++j) {
            cc1 = fmaf(b1[j], W2[(D + j) * D + dd], cc1);
            cc2 = fmaf(b2[j], Ww[j * D + dd], cc2);
        }
        c1[dd] = cc1;
        c2[dd] = cc2;
    }
}

// ---------------------------------------------------------------------------
// Per-edge segment boundaries: seg[e] = lower_bound(edges, e). One thread/edge,
// all 50001 binary searches latency-parallel.
// ---------------------------------------------------------------------------
__global__ void k_seg(const int* __restrict__ edges, int* __restrict__ seg) {
    int e = blockIdx.x * blockDim.x + threadIdx.x;
    if (e > N_EDGES) return;
    int lo = 0, hi = NNZ;
    while (lo < hi) { int mid = (lo + hi) >> 1; if (edges[mid] < e) lo = mid + 1; else hi = mid; }
    seg[e] = lo;
}

// ---------------------------------------------------------------------------
// Histogram of vertex -> cnt  (node degrees, needed by epilogue)
// ---------------------------------------------------------------------------
__global__ void k_hist(const int* __restrict__ vertex, int* __restrict__ cnt) {
    int i = blockIdx.x * blockDim.x + threadIdx.x;
    int stride = gridDim.x * blockDim.x;
    for (; i < NNZ; i += stride) atomicAdd(&cnt[vertex[i]], 1);
}

// ---------------------------------------------------------------------------
// K2: per-edge (one wave per edge).
//   Xe = sum_i a_i * X[v_i]        (4x-unrolled gather, 2 halves)
//   fe = Xe @ M1 + (sum a_i) * c1  (in-register GEMV)
//   scatter: AccH[v] += fe as packed f16 pairs. Lane layout: pair p=d>>1,
//   quarter q=(h<<1)|(d&1); the 16 lanes of a quarter hit ONE 64B node row
//   per atomic instruction; quarters split the incidence list 4 ways.
// ---------------------------------------------------------------------------
__global__ void k2_edge(const float* __restrict__ X,
                        const float* __restrict__ atts,
                        const int* __restrict__ vertex,
                        const int* __restrict__ seg,
                        const float* __restrict__ M1,
                        const float* __restrict__ c1,
                        __half* __restrict__ AccH) {
    __shared__ float Ms[D * D];
    __shared__ float cs[D];
    for (int i = threadIdx.x; i < D * D; i += blockDim.x) Ms[i] = M1[i];
    if (threadIdx.x < D) cs[threadIdx.x] = c1[threadIdx.x];
    __syncthreads();

    int wave = threadIdx.x >> 6;
    int lane = threadIdx.x & 63;
    int d    = lane & 31;
    int h    = lane >> 5;
    int e    = blockIdx.x * (blockDim.x >> 6) + wave;
    if (e >= N_EDGES) return;

    int start = seg[e];
    int end   = seg[e + 1];

    // gather phase: 2 incidences per wave-iter, unrolled x4 for MLP
    float acc0 = 0.f, acc1 = 0.f, acc2 = 0.f, acc3 = 0.f, sa = 0.f;
    int i = start + h;
    for (; i + 6 < end; i += 8) {
        int   v0 = vertex[i],     v1 = vertex[i + 2], v2 = vertex[i + 4], v3 = vertex[i + 6];
        float a0 = atts[i],       a1 = atts[i + 2],   a2 = atts[i + 4],   a3 = atts[i + 6];
        acc0 = fmaf(a0, X[v0 * D + d], acc0);
        acc1 = fmaf(a1, X[v1 * D + d], acc1);
        acc2 = fmaf(a2, X[v2 * D + d], acc2);
        acc3 = fmaf(a3, X[v3 * D + d], acc3);
        sa += (a0 + a1) + (a2 + a3);
    }
    for (; i < end; i += 2) {
        int v = vertex[i];
        float a = atts[i];
        acc0 = fmaf(a, X[v * D + d], acc0);
        sa += a;
    }
    float acc = (acc0 + acc1) + (acc2 + acc3);
    acc += __shfl(acc, lane ^ 32, 64);   // both halves now hold full Xe[d]
    sa  += __shfl(sa,  lane ^ 32, 64);

    // fe[d] = sum_k Xe[k] * M1[k][d] + sa * c1[d]
    float fe = sa * cs[d];
#pragma unroll
    for (int k = 0; k < D; ++k) {
        float xk = __shfl(acc, k, 32);
        fe = fmaf(xk, Ms[k * D + d], fe);
    }

    // pack (fe[2p], fe[2p+1]) in every lane of pair p
    float other = __shfl(fe, lane ^ 1, 64);
    float flo = (d & 1) ? other : fe;
    float fhi = (d & 1) ? fe : other;
    __half2 hv = __floats2half2_rn(flo, fhi);
    unsigned int hbits = *reinterpret_cast<unsigned int*>(&hv);

    int p = d >> 1;
    int q = (h << 1) | (d & 1);          // quarter of the incidence list
    char* base = (char*)AccH + (size_t)p * 4;

    int i2 = start + q;
    for (; i2 + 4 < end; i2 += 8) {
        int va = vertex[i2];
        int vb = vertex[i2 + 4];
        char* pa = base + (size_t)va * 64;
        char* pb = base + (size_t)vb * 64;
        asm volatile("global_atomic_pk_add_f16 %0, %1, off" :: "v"(pa), "v"(hbits) : "memory");
        asm volatile("global_atomic_pk_add_f16 %0, %1, off" :: "v"(pb), "v"(hbits) : "memory");
    }
    if (i2 < end) {
        int va = vertex[i2];
        char* pa = base + (size_t)va * 64;
        asm volatile("global_atomic_pk_add_f16 %0, %1, off" :: "v"(pa), "v"(hbits) : "memory");
    }
}

// ---------------------------------------------------------------------------
// K3: per-node streaming epilogue (half-wave per node).
//   s1 = X @ A2 + c2 ;  s2 = (AccH + X0) @ W
//   out = 0.5*(deg*s1 + s2) + b
// ---------------------------------------------------------------------------
__global__ void k3_node(const float* __restrict__ X,
                        const float* __restrict__ X0,
                        const __half* __restrict__ AccH,
                        const int* __restrict__ cnt,
                        const float* __restrict__ A2,
                        const float* __restrict__ c2,
                        const float* __restrict__ Ww,
                        const float* __restrict__ bw,
                        float* __restrict__ out) {
    __shared__ float As[D * D];
    __shared__ float Ws[D * D];
    __shared__ float c2s[D];
    __shared__ float bws[D];
    for (int i = threadIdx.x; i < D * D; i += blockDim.x) {
        As[i] = A2[i];
        Ws[i] = Ww[i];
    }
    if (threadIdx.x < D) { c2s[threadIdx.x] = c2[threadIdx.x]; bws[threadIdx.x] = bw[threadIdx.x]; }
    __syncthreads();

    int half = threadIdx.x >> 5;
    int j    = threadIdx.x & 31;
    int node = blockIdx.x * (blockDim.x >> 5) + half;
    if (node >= N_NODES) return;

    float x  = X[node * D + j];
    float s1 = c2s[j];
#pragma unroll
    for (int k = 0; k < D; ++k) {
        float xk = __shfl(x, k, 32);
        s1 = fmaf(xk, As[k * D + j], s1);
    }

    float sf = __half2float(AccH[node * D + j]);
    float t  = sf + X0[node * D + j];
    float s2 = 0.f;
#pragma unroll
    for (int k = 0; k < D; ++k) {
        float tk = __shfl(t, k, 32);
        s2 = fmaf(tk, Ws[k * D + j], s2);
    }

    out[node * D + j] = 0.5f * fmaf((float)cnt[node], s1, s2) + bws[j];
}

// ---------------------------------------------------------------------------
extern "C" void kernel_launch(void* const* d_in, const int* in_sizes, int n_in,
                              void* d_out, int out_size, void* d_ws, size_t ws_size,
                              hipStream_t stream) {
    const float* X      = (const float*)d_in[0];
    const float* X0     = (const float*)d_in[1];
    const float* atts   = (const float*)d_in[2];
    const float* W1w    = (const float*)d_in[3];
    const float* W1b    = (const float*)d_in[4];
    const float* W2w    = (const float*)d_in[5];
    const float* W2b    = (const float*)d_in[6];
    const float* Ww     = (const float*)d_in[7];
    const float* Wb     = (const float*)d_in[8];
    const int*   vertex = (const int*)d_in[9];
    const int*   edges  = (const int*)d_in[10];
    float*       out    = (float*)d_out;

    char* ws = (char*)d_ws;
    __half* AccH = (__half*)(ws);                    // N_NODES*32*2 = 6,400,000 B
    int*    cnt  = (int*)  (ws + 6400000);           // 400,000 B (contiguous w/ AccH)
    float*  M1   = (float*)(ws + 6800128);           // 4 KB
    float*  A2   = (float*)(ws + 6804224);           // 4 KB
    float*  c1   = (float*)(ws + 6808320);           // 128 B
    float*  c2   = (float*)(ws + 6808448);           // 128 B
    int*    seg  = (int*)  (ws + 6808576);           // (N_EDGES+1)*4

    // zero AccH + cnt in one shot
    hipMemsetAsync(ws, 0, 6800000, stream);

    k0_weights<<<1, 1024, 0, stream>>>(W1w, W1b, W2w, W2b, Ww, M1, c1, A2, c2);
    k_seg     <<<(N_EDGES + 256) / 256, 256, 0, stream>>>(edges, seg);
    k_hist    <<<1024, 256, 0, stream>>>(vertex, cnt);
    k2_edge   <<<(N_EDGES + 3) / 4, 256, 0, stream>>>(X, atts, vertex, seg, M1, c1, AccH);
    k3_node   <<<(N_NODES + 7) / 8, 256, 0, stream>>>(X, X0, AccH, cnt, A2, c2, Ww, Wb, out);
}